// Round 1
// baseline (374.508 us; speedup 1.0000x reference)
//
#include <hip/hip_runtime.h>

#define LL   2048
#define DIM  512
#define NH   8
#define HD   64
#define BHN  16      // batch * NH
#define NC   64      // chunks along L
#define CH   32      // chunk length = LL/NC
#define EPSF 1e-8f

// ---------------- Kernel 1: per-chunk product of A (A_0 := 1) ----------------
__global__ __launch_bounds__(64) void chunkprod_kernel(const float* __restrict__ S,
                                                       float* __restrict__ U) {
    int c = blockIdx.x, bh = blockIdx.y;
    int b = bh >> 3, h = bh & 7;
    int d = threadIdx.x;
    int l0 = c * CH;
    size_t base = ((size_t)b * LL + l0) * DIM + h * HD + d;
    float p = 1.0f;
    for (int l = 0; l < CH; ++l) {
        float a = S[base + (size_t)l * DIM];
        if (l0 + l >= 1) p *= a;   // position 0's A is replaced by 1
    }
    U[((size_t)bh * NC + c) * HD + d] = p;
}

// ---------------- Kernel 2: exclusive scan of chunk products -----------------
__global__ __launch_bounds__(64) void chunkscan_kernel(const float* __restrict__ U,
                                                       float* __restrict__ St) {
    int bh = blockIdx.x;
    int d = threadIdx.x;
    float p = 1.0f;
    for (int c = 0; c < NC; ++c) {
        size_t o = ((size_t)bh * NC + c) * HD + d;
        St[o] = p;
        p *= U[o];
    }
}

// ------- Kernel 3: rescan chunks, emit X = C*P, Y = B/D, diag = C.B ----------
__global__ __launch_bounds__(64) void apply_kernel(const float* __restrict__ Bg,
                                                   const float* __restrict__ Cg,
                                                   const float* __restrict__ S,
                                                   const float* __restrict__ St,
                                                   float* __restrict__ X,
                                                   float* __restrict__ Y,
                                                   float* __restrict__ diag) {
    int c = blockIdx.x, bh = blockIdx.y;
    int b = bh >> 3, h = bh & 7;
    int d = threadIdx.x;
    int l0 = c * CH;
    size_t gbase = ((size_t)b * LL + l0) * DIM + h * HD + d;
    float p = St[((size_t)bh * NC + c) * HD + d];   // P[l0] = prod_{k=1..l0-1} A_k
    for (int l = 0; l < CH; ++l) {
        int gl = l0 + l;
        size_t gi = gbase + (size_t)l * DIM;
        float a = S[gi], bv = Bg[gi], cv = Cg[gi];
        float Dv = (gl == 0) ? 1.0f : (p + EPSF);
        size_t o = ((size_t)bh * LL + gl) * HD + d;
        X[o] = cv * p;          // mirror reference: Ch*P and Bh/D formed separately
        Y[o] = bv / Dv;
        float tsum = cv * bv;   // diagonal C_i . B_i via wave reduce (64 lanes = d)
        #pragma unroll
        for (int off = 1; off < 64; off <<= 1) tsum += __shfl_xor(tsum, off);
        if (d == 0) diag[(size_t)bh * LL + gl] = tsum;
        if (gl >= 1) p *= a;    // advance to P[gl+1]
    }
}

// ---------------- Kernel 4: masked GEMM  T = X Y^T  (lower), diag, 0 ---------
// 128x128 tile, K=64 in two 32-wide passes (LDS 32KB -> 4 blocks/CU).
// LDS k-major with XOR swizzle col' = col ^ (4*(k>>2)): transpose-writes and
// float4 reads are both <=2-way bank aliased (free on CDNA4, m136).
__global__ __launch_bounds__(256) void gemm_kernel(const float* __restrict__ X,
                                                   const float* __restrict__ Y,
                                                   const float* __restrict__ diag,
                                                   float* __restrict__ out) {
    int tj = blockIdx.x, ti = blockIdx.y, bh = blockIdx.z;
    size_t obase = (size_t)bh * LL * LL;
    int i0 = ti * 128, j0 = tj * 128;
    int t = threadIdx.x;

    if (tj > ti) {   // fully strict-upper tile: zero-fill only (uniform branch)
        float4 z = make_float4(0.f, 0.f, 0.f, 0.f);
        int col4 = t & 31, row0 = t >> 5;
        float* ob = out + obase + (size_t)i0 * LL + j0;
        #pragma unroll
        for (int r = 0; r < 16; ++r)
            *((float4*)(ob + (size_t)(row0 + 8 * r) * LL) + col4) = z;
        return;
    }

    __shared__ float Xs[32 * 128];
    __shared__ float Ys[32 * 128];
    int tx = t & 15, ty = t >> 4;

    float acc[8][8];
    #pragma unroll
    for (int i = 0; i < 8; ++i)
        #pragma unroll
        for (int j = 0; j < 8; ++j) acc[i][j] = 0.f;

    const float* Xg = X + ((size_t)bh * LL + i0) * HD;
    const float* Yg = Y + ((size_t)bh * LL + j0) * HD;

    for (int kt = 0; kt < 2; ++kt) {
        // ---- stage: 128 rows x 32 k, transposed into k-major LDS ----
        {
            int kq = t & 7;           // float4 index within the 32-k slice
            int r0 = t >> 3;          // 0..31
            #pragma unroll
            for (int it = 0; it < 4; ++it) {
                int r = r0 + 32 * it;
                float4 vx = *((const float4*)(Xg + (size_t)r * HD) + (kq + 8 * kt));
                float4 vy = *((const float4*)(Yg + (size_t)r * HD) + (kq + 8 * kt));
                int col = r ^ (4 * kq);       // swizzle: (k>>2)&15 == kq here
                int kb = (4 * kq) * 128;
                Xs[kb + col] = vx.x; Xs[kb + 128 + col] = vx.y;
                Xs[kb + 256 + col] = vx.z; Xs[kb + 384 + col] = vx.w;
                Ys[kb + col] = vy.x; Ys[kb + 128 + col] = vy.y;
                Ys[kb + 256 + col] = vy.z; Ys[kb + 384 + col] = vy.w;
            }
        }
        __syncthreads();
        // ---- compute 32 k-steps ----
        for (int k = 0; k < 32; ++k) {
            int swz = 4 * (k >> 2);
            const float4 xa = *(const float4*)&Xs[k * 128 + ((4 * ty) ^ swz)];
            const float4 xb = *(const float4*)&Xs[k * 128 + (((4 * ty) ^ swz) + 64)];
            const float4 ya = *(const float4*)&Ys[k * 128 + ((4 * tx) ^ swz)];
            const float4 yb = *(const float4*)&Ys[k * 128 + (((4 * tx) ^ swz) + 64)];
            float xv[8] = {xa.x, xa.y, xa.z, xa.w, xb.x, xb.y, xb.z, xb.w};
            float yv[8] = {ya.x, ya.y, ya.z, ya.w, yb.x, yb.y, yb.z, yb.w};
            #pragma unroll
            for (int i = 0; i < 8; ++i)
                #pragma unroll
                for (int j = 0; j < 8; ++j)
                    acc[i][j] += xv[i] * yv[j];
        }
        __syncthreads();
    }

    // ---- epilogue ----
    if (tj < ti) {   // fully strict-lower: store as-is
        #pragma unroll
        for (int ii = 0; ii < 2; ++ii)
            #pragma unroll
            for (int r = 0; r < 4; ++r) {
                int i = 64 * ii + 4 * ty + r;
                float* ob = out + obase + (size_t)(i0 + i) * LL + j0;
                #pragma unroll
                for (int jj = 0; jj < 2; ++jj) {
                    float4 v = make_float4(acc[ii * 4 + r][jj * 4 + 0],
                                           acc[ii * 4 + r][jj * 4 + 1],
                                           acc[ii * 4 + r][jj * 4 + 2],
                                           acc[ii * 4 + r][jj * 4 + 3]);
                    *((float4*)ob + (16 * jj + tx)) = v;
                }
            }
    } else {         // diagonal tile: mask j>i to 0, j==i to diag
        #pragma unroll
        for (int ii = 0; ii < 2; ++ii)
            #pragma unroll
            for (int r = 0; r < 4; ++r) {
                int i = 64 * ii + 4 * ty + r;
                int gi = i0 + i;
                float dv = diag[(size_t)bh * LL + gi];
                float* ob = out + obase + (size_t)gi * LL + j0;
                #pragma unroll
                for (int jj = 0; jj < 2; ++jj) {
                    float4 v;
                    float* vp = (float*)&v;
                    #pragma unroll
                    for (int s = 0; s < 4; ++s) {
                        int gj = j0 + 64 * jj + 4 * tx + s;
                        float val = acc[ii * 4 + r][jj * 4 + s];
                        vp[s] = (gj < gi) ? val : ((gj == gi) ? dv : 0.f);
                    }
                    *((float4*)ob + (16 * jj + tx)) = v;
                }
            }
    }
}

extern "C" void kernel_launch(void* const* d_in, const int* in_sizes, int n_in,
                              void* d_out, int out_size, void* d_ws, size_t ws_size,
                              hipStream_t stream) {
    const float* Bg = (const float*)d_in[0];
    const float* Cg = (const float*)d_in[1];
    const float* S  = (const float*)d_in[2];
    float* out = (float*)d_out;

    char* ws = (char*)d_ws;
    size_t xy_bytes = (size_t)BHN * LL * HD * sizeof(float);   // 8 MB each
    float* X    = (float*)(ws);
    float* Y    = (float*)(ws + xy_bytes);
    float* diag = (float*)(ws + 2 * xy_bytes);
    float* U    = (float*)(ws + 2 * xy_bytes + (size_t)BHN * LL * sizeof(float));
    float* St   = (float*)(ws + 2 * xy_bytes + (size_t)BHN * LL * sizeof(float)
                              + (size_t)BHN * NC * HD * sizeof(float));

    chunkprod_kernel<<<dim3(NC, BHN), 64, 0, stream>>>(S, U);
    chunkscan_kernel<<<BHN, 64, 0, stream>>>(U, St);
    apply_kernel<<<dim3(NC, BHN), 64, 0, stream>>>(Bg, Cg, S, St, X, Y, diag);
    gemm_kernel<<<dim3(16, 16, BHN), 256, 0, stream>>>(X, Y, diag, out);
}

// Round 2
// 329.072 us; speedup vs baseline: 1.1381x; 1.1381x over previous
//
#include <hip/hip_runtime.h>
#include <hip/hip_bf16.h>

#define LL   2048
#define DIM  512
#define HD   64
#define BHN  16      // batch * NH
#define NC   64      // chunks along L
#define CH   32      // chunk length = LL/NC
#define EPSF 1e-8f

typedef __attribute__((ext_vector_type(8))) short bf16x8;   // 8 bf16 = 4 VGPRs
typedef __attribute__((ext_vector_type(4))) float f32x4;    // MFMA C/D

// ---------------- Kernel 1: per-chunk product of A (A_0 := 1) ----------------
__global__ __launch_bounds__(64) void chunkprod_kernel(const float* __restrict__ S,
                                                       float* __restrict__ U) {
    int c = blockIdx.x, bh = blockIdx.y;
    int b = bh >> 3, h = bh & 7;
    int d = threadIdx.x;
    int l0 = c * CH;
    size_t base = ((size_t)b * LL + l0) * DIM + h * HD + d;
    float p = 1.0f;
    for (int l = 0; l < CH; ++l) {
        float a = S[base + (size_t)l * DIM];
        if (l0 + l >= 1) p *= a;   // position 0's A is replaced by 1
    }
    U[((size_t)bh * NC + c) * HD + d] = p;
}

// ---------------- Kernel 2: exclusive scan of chunk products -----------------
__global__ __launch_bounds__(64) void chunkscan_kernel(const float* __restrict__ U,
                                                       float* __restrict__ St) {
    int bh = blockIdx.x;
    int d = threadIdx.x;
    float p = 1.0f;
    for (int c = 0; c < NC; ++c) {
        size_t o = ((size_t)bh * NC + c) * HD + d;
        St[o] = p;
        p *= U[o];
    }
}

// --- Kernel 3: rescan chunks, emit X = bf16(C*P), Y = bf16(B/D), diag = C.B --
__global__ __launch_bounds__(64) void apply_kernel(const float* __restrict__ Bg,
                                                   const float* __restrict__ Cg,
                                                   const float* __restrict__ S,
                                                   const float* __restrict__ St,
                                                   __hip_bfloat16* __restrict__ X,
                                                   __hip_bfloat16* __restrict__ Y,
                                                   float* __restrict__ diag) {
    int c = blockIdx.x, bh = blockIdx.y;
    int b = bh >> 3, h = bh & 7;
    int d = threadIdx.x;
    int l0 = c * CH;
    size_t gbase = ((size_t)b * LL + l0) * DIM + h * HD + d;
    float p = St[((size_t)bh * NC + c) * HD + d];   // P[l0] = prod_{k=1..l0-1} A_k
    for (int l = 0; l < CH; ++l) {
        int gl = l0 + l;
        size_t gi = gbase + (size_t)l * DIM;
        float a = S[gi], bv = Bg[gi], cv = Cg[gi];
        float Dv = (gl == 0) ? 1.0f : (p + EPSF);
        size_t o = ((size_t)bh * LL + gl) * HD + d;
        X[o] = __float2bfloat16(cv * p);    // mirror reference: C*P and B/D separate
        Y[o] = __float2bfloat16(bv / Dv);
        float tsum = cv * bv;   // diagonal C_i . B_i exact in fp32 (wave reduce)
        #pragma unroll
        for (int off = 1; off < 64; off <<= 1) tsum += __shfl_xor(tsum, off);
        if (d == 0) diag[(size_t)bh * LL + gl] = tsum;
        if (gl >= 1) p *= a;    // advance to P[gl+1]
    }
}

// ------------- Kernel 4: MFMA bf16 GEMM  T = X Y^T (lower), diag, 0 ----------
// 128x128 tile, K=64 one-shot. LDS 2x16KB, 16B-chunk XOR swizzle (<=2-way, free).
// 4 waves, each 64x64 via 4x4 tiles of mfma_f32_16x16x32_bf16.
__global__ __launch_bounds__(256) void gemm_kernel(const __hip_bfloat16* __restrict__ X,
                                                   const __hip_bfloat16* __restrict__ Y,
                                                   const float* __restrict__ diag,
                                                   float* __restrict__ out) {
    int tj = blockIdx.x, ti = blockIdx.y, bh = blockIdx.z;
    size_t obase = (size_t)bh * LL * LL;
    int i0 = ti * 128, j0 = tj * 128;
    int t = threadIdx.x;

    if (tj > ti) {   // fully strict-upper tile: zero-fill only (uniform branch)
        float4 z = make_float4(0.f, 0.f, 0.f, 0.f);
        int col4 = t & 31, row0 = t >> 5;
        float* ob = out + obase + (size_t)i0 * LL + j0;
        #pragma unroll
        for (int r = 0; r < 16; ++r)
            *((float4*)(ob + (size_t)(row0 + 8 * r) * LL) + col4) = z;
        return;
    }

    __shared__ short Xs[128 * 64];   // bf16 bits, row-major 64/row, swizzled chunks
    __shared__ short Ys[128 * 64];

    // ---- stage 128 rows x 64 bf16 per operand (16B/lane x 4 passes) ----
    {
        const float4* Xg4 = (const float4*)(X + ((size_t)bh * LL + i0) * HD);
        const float4* Yg4 = (const float4*)(Y + ((size_t)bh * LL + j0) * HD);
        int chunk = t & 7, r0 = t >> 3;    // chunk: 16B unit within row; r0: 0..31
        int sc = (chunk ^ (r0 & 7)) * 8;   // row&7 == r0&7 (rows step by 32)
        #pragma unroll
        for (int p = 0; p < 4; ++p) {
            int row = r0 + 32 * p;
            float4 vx = Xg4[row * 8 + chunk];
            float4 vy = Yg4[row * 8 + chunk];
            *(float4*)&Xs[row * 64 + sc] = vx;
            *(float4*)&Ys[row * 64 + sc] = vy;
        }
    }
    __syncthreads();

    // ---- compute: wave (wi,wj) owns 64x64; 4x4 tiles of 16x16, K=64 ----
    int lane = t & 63, wv = t >> 6;
    int wi = wv >> 1, wj = wv & 1;
    int l15 = lane & 15, q = lane >> 4;

    f32x4 acc[4][4] = {};
    #pragma unroll
    for (int kc = 0; kc < 2; ++kc) {
        bf16x8 af[4], bf[4];
        #pragma unroll
        for (int mt = 0; mt < 4; ++mt) {
            int row = 64 * wi + 16 * mt + l15;           // A[m][k]: m=lane&15
            int sc = ((4 * kc + q) ^ (row & 7)) * 8;     // k-chunk = 4*kc + quad
            af[mt] = *(const bf16x8*)&Xs[row * 64 + sc];
        }
        #pragma unroll
        for (int nt = 0; nt < 4; ++nt) {
            int row = 64 * wj + 16 * nt + l15;           // B[k][n]: n=lane&15
            int sc = ((4 * kc + q) ^ (row & 7)) * 8;
            bf[nt] = *(const bf16x8*)&Ys[row * 64 + sc];
        }
        #pragma unroll
        for (int mt = 0; mt < 4; ++mt)
            #pragma unroll
            for (int nt = 0; nt < 4; ++nt)
                acc[mt][nt] = __builtin_amdgcn_mfma_f32_16x16x32_bf16(
                    af[mt], bf[nt], acc[mt][nt], 0, 0, 0);
    }

    // ---- epilogue: C/D layout col=lane&15, row=quad*4+reg ----
    int i_base = i0 + 64 * wi, j_base = j0 + 64 * wj;
    if (tj < ti) {   // fully strict-lower: store everything
        #pragma unroll
        for (int mt = 0; mt < 4; ++mt)
            #pragma unroll
            for (int reg = 0; reg < 4; ++reg) {
                int gi = i_base + 16 * mt + 4 * q + reg;
                float* ob = out + obase + (size_t)gi * LL + j_base;
                #pragma unroll
                for (int nt = 0; nt < 4; ++nt)
                    ob[16 * nt + l15] = acc[mt][nt][reg];
            }
    } else {         // diagonal tile: mask j>i to 0, j==i to diag
        #pragma unroll
        for (int mt = 0; mt < 4; ++mt)
            #pragma unroll
            for (int reg = 0; reg < 4; ++reg) {
                int gi = i_base + 16 * mt + 4 * q + reg;
                float dv = diag[(size_t)bh * LL + gi];
                float* ob = out + obase + (size_t)gi * LL + j_base;
                #pragma unroll
                for (int nt = 0; nt < 4; ++nt) {
                    int gj = j_base + 16 * nt + l15;
                    float v = acc[mt][nt][reg];
                    ob[16 * nt + l15] = (gj < gi) ? v : ((gj == gi) ? dv : 0.f);
                }
            }
    }
}

extern "C" void kernel_launch(void* const* d_in, const int* in_sizes, int n_in,
                              void* d_out, int out_size, void* d_ws, size_t ws_size,
                              hipStream_t stream) {
    const float* Bg = (const float*)d_in[0];
    const float* Cg = (const float*)d_in[1];
    const float* S  = (const float*)d_in[2];
    float* out = (float*)d_out;

    char* ws = (char*)d_ws;
    size_t xy_bytes = (size_t)BHN * LL * HD * sizeof(__hip_bfloat16);  // 4 MB each
    __hip_bfloat16* X = (__hip_bfloat16*)(ws);
    __hip_bfloat16* Y = (__hip_bfloat16*)(ws + xy_bytes);
    float* diag = (float*)(ws + 2 * xy_bytes);
    float* U    = (float*)(ws + 2 * xy_bytes + (size_t)BHN * LL * sizeof(float));
    float* St   = (float*)(ws + 2 * xy_bytes + (size_t)BHN * LL * sizeof(float)
                              + (size_t)BHN * NC * HD * sizeof(float));

    chunkprod_kernel<<<dim3(NC, BHN), 64, 0, stream>>>(S, U);
    chunkscan_kernel<<<BHN, 64, 0, stream>>>(U, St);
    apply_kernel<<<dim3(NC, BHN), 64, 0, stream>>>(Bg, Cg, S, St, X, Y, diag);
    gemm_kernel<<<dim3(16, 16, BHN), 256, 0, stream>>>(X, Y, diag, out);
}

// Round 4
// 304.644 us; speedup vs baseline: 1.2293x; 1.0802x over previous
//
#include <hip/hip_runtime.h>
#include <hip/hip_bf16.h>

#define LL   2048
#define DIM  512
#define HD   64
#define BHN  16      // batch * NH
#define NC   128     // chunks along L
#define CH   16      // chunk length = LL/NC
#define GC   8       // chunks per scan-group (NC / 16 groups)
#define EPSF 1e-8f

typedef __attribute__((ext_vector_type(8))) short bf16x8;   // 8 bf16 = 4 VGPRs
typedef __attribute__((ext_vector_type(4))) float f32x4;    // MFMA C/D + native 16B vector

__device__ __forceinline__ void nt_store(float* p, float v) {
    __builtin_nontemporal_store(v, p);
}
__device__ __forceinline__ void nt_store4(f32x4* p, f32x4 v) {
    __builtin_nontemporal_store(v, p);
}

// ---------------- Kernel 1: per-chunk product of A (A_0 := 1) ----------------
__global__ __launch_bounds__(64) void chunkprod_kernel(const float* __restrict__ S,
                                                       float* __restrict__ U) {
    int c = blockIdx.x, bh = blockIdx.y;
    int b = bh >> 3, h = bh & 7;
    int d = threadIdx.x;
    int l0 = c * CH;
    size_t base = ((size_t)b * LL + l0) * DIM + h * HD + d;
    float p = 1.0f;
    #pragma unroll
    for (int l = 0; l < CH; ++l) {
        float a = S[base + (size_t)l * DIM];
        if (l0 + l >= 1) p *= a;   // position 0's A is replaced by 1
    }
    U[((size_t)bh * NC + c) * HD + d] = p;
}

// ------- Kernel 2: parallel exclusive scan of chunk products (per bh) --------
// 1024 threads: group g = t>>6 owns GC=8 chunks for channel d = t&63.
__global__ __launch_bounds__(1024) void chunkscan_kernel(const float* __restrict__ U,
                                                         float* __restrict__ St) {
    int bh = blockIdx.x;
    int t = threadIdx.x;
    int g = t >> 6, d = t & 63;
    int c0 = g * GC;
    float u[GC];
    float prod = 1.0f;
    #pragma unroll
    for (int k = 0; k < GC; ++k) {
        u[k] = U[((size_t)bh * NC + c0 + k) * HD + d];
        prod *= u[k];
    }
    __shared__ float Ls[16][64];
    Ls[g][d] = prod;
    __syncthreads();
    float run = 1.0f;
    for (int gg = 0; gg < g; ++gg) run *= Ls[gg][d];   // g uniform per wave
    #pragma unroll
    for (int k = 0; k < GC; ++k) {
        St[((size_t)bh * NC + c0 + k) * HD + d] = run;
        run *= u[k];
    }
}

// --------------- Kernel 3: diag[bh,l] = C_l . B_l (one wave per row) ---------
__global__ __launch_bounds__(256) void diag_kernel(const float* __restrict__ Bg,
                                                   const float* __restrict__ Cg,
                                                   float* __restrict__ diag) {
    int w = threadIdx.x >> 6, lane = threadIdx.x & 63;
    int flat = blockIdx.x * 4 + w;          // flat = bh*LL + l
    int bh = flat >> 11, l = flat & (LL - 1);
    int b = bh >> 3, h = bh & 7;
    size_t gi = ((size_t)b * LL + l) * DIM + h * HD + lane;
    float tsum = Cg[gi] * Bg[gi];
    #pragma unroll
    for (int off = 1; off < 64; off <<= 1) tsum += __shfl_xor(tsum, off);
    if (lane == 0) diag[(size_t)bh * LL + l] = tsum;
}

// -------- Kernel 4: rescan chunks, emit X = bf16(C*P), Y = bf16(B/D) ---------
__global__ __launch_bounds__(64) void apply_kernel(const float* __restrict__ Bg,
                                                   const float* __restrict__ Cg,
                                                   const float* __restrict__ S,
                                                   const float* __restrict__ St,
                                                   __hip_bfloat16* __restrict__ X,
                                                   __hip_bfloat16* __restrict__ Y) {
    int c = blockIdx.x, bh = blockIdx.y;
    int b = bh >> 3, h = bh & 7;
    int d = threadIdx.x;
    int l0 = c * CH;
    size_t gbase = ((size_t)b * LL + l0) * DIM + h * HD + d;
    float p = St[((size_t)bh * NC + c) * HD + d];   // P[l0] = prod_{k=1..l0-1} A_k
    #pragma unroll
    for (int l = 0; l < CH; ++l) {
        int gl = l0 + l;
        size_t gi = gbase + (size_t)l * DIM;
        float a = S[gi], bv = Bg[gi], cv = Cg[gi];
        float Dv = (gl == 0) ? 1.0f : (p + EPSF);
        size_t o = ((size_t)bh * LL + gl) * HD + d;
        X[o] = __float2bfloat16(cv * p);    // mirror reference: C*P and B/D separate
        Y[o] = __float2bfloat16(bv / Dv);
        if (gl >= 1) p *= a;                // advance to P[gl+1]
    }
}

// ------------- Kernel 5: MFMA bf16 GEMM  T = X Y^T (lower), diag, 0 ----------
// 128x128 tile, K=64 one-shot. LDS 2x16KB, 16B-chunk XOR swizzle (<=2-way, free).
// 4 waves, each 64x64 via 4x4 tiles of mfma_f32_16x16x32_bf16.
__global__ __launch_bounds__(256) void gemm_kernel(const __hip_bfloat16* __restrict__ X,
                                                   const __hip_bfloat16* __restrict__ Y,
                                                   const float* __restrict__ diag,
                                                   float* __restrict__ out) {
    int tj = blockIdx.x, ti = blockIdx.y, bh = blockIdx.z;
    size_t obase = (size_t)bh * LL * LL;
    int i0 = ti * 128, j0 = tj * 128;
    int t = threadIdx.x;

    if (tj > ti) {   // fully strict-upper tile: zero-fill only (uniform branch)
        f32x4 z = {0.f, 0.f, 0.f, 0.f};
        int col4 = t & 31, row0 = t >> 5;
        float* ob = out + obase + (size_t)i0 * LL + j0;
        #pragma unroll
        for (int r = 0; r < 16; ++r)
            nt_store4((f32x4*)(ob + (size_t)(row0 + 8 * r) * LL) + col4, z);
        return;
    }

    __shared__ short Xs[128 * 64];   // bf16 bits, row-major 64/row, swizzled chunks
    __shared__ short Ys[128 * 64];

    // ---- stage 128 rows x 64 bf16 per operand (16B/lane x 4 passes) ----
    {
        const f32x4* Xg4 = (const f32x4*)(X + ((size_t)bh * LL + i0) * HD);
        const f32x4* Yg4 = (const f32x4*)(Y + ((size_t)bh * LL + j0) * HD);
        int chunk = t & 7, r0 = t >> 3;    // chunk: 16B unit within row; r0: 0..31
        int sc = (chunk ^ (r0 & 7)) * 8;   // row&7 == r0&7 (rows step by 32)
        #pragma unroll
        for (int p = 0; p < 4; ++p) {
            int row = r0 + 32 * p;
            f32x4 vx = Xg4[row * 8 + chunk];
            f32x4 vy = Yg4[row * 8 + chunk];
            *(f32x4*)&Xs[row * 64 + sc] = vx;
            *(f32x4*)&Ys[row * 64 + sc] = vy;
        }
    }
    __syncthreads();

    // ---- compute: wave (wi,wj) owns 64x64; 4x4 tiles of 16x16, K=64 ----
    int lane = t & 63, wv = t >> 6;
    int wi = wv >> 1, wj = wv & 1;
    int l15 = lane & 15, q = lane >> 4;

    f32x4 acc[4][4] = {};
    #pragma unroll
    for (int kc = 0; kc < 2; ++kc) {
        bf16x8 af[4], bf[4];
        #pragma unroll
        for (int mt = 0; mt < 4; ++mt) {
            int row = 64 * wi + 16 * mt + l15;           // A[m][k]: m=lane&15
            int sc = ((4 * kc + q) ^ (row & 7)) * 8;     // k-chunk = 4*kc + quad
            af[mt] = *(const bf16x8*)&Xs[row * 64 + sc];
        }
        #pragma unroll
        for (int nt = 0; nt < 4; ++nt) {
            int row = 64 * wj + 16 * nt + l15;           // B[k][n]: n=lane&15
            int sc = ((4 * kc + q) ^ (row & 7)) * 8;
            bf[nt] = *(const bf16x8*)&Ys[row * 64 + sc];
        }
        #pragma unroll
        for (int mt = 0; mt < 4; ++mt)
            #pragma unroll
            for (int nt = 0; nt < 4; ++nt)
                acc[mt][nt] = __builtin_amdgcn_mfma_f32_16x16x32_bf16(
                    af[mt], bf[nt], acc[mt][nt], 0, 0, 0);
    }

    // ---- epilogue: C/D layout col=lane&15, row=quad*4+reg ----
    int i_base = i0 + 64 * wi, j_base = j0 + 64 * wj;
    if (tj < ti) {   // fully strict-lower: store everything
        #pragma unroll
        for (int mt = 0; mt < 4; ++mt)
            #pragma unroll
            for (int reg = 0; reg < 4; ++reg) {
                int gi = i_base + 16 * mt + 4 * q + reg;
                float* ob = out + obase + (size_t)gi * LL + j_base;
                #pragma unroll
                for (int nt = 0; nt < 4; ++nt)
                    nt_store(ob + 16 * nt + l15, acc[mt][nt][reg]);
            }
    } else {         // diagonal tile: mask j>i to 0, j==i to diag
        #pragma unroll
        for (int mt = 0; mt < 4; ++mt)
            #pragma unroll
            for (int reg = 0; reg < 4; ++reg) {
                int gi = i_base + 16 * mt + 4 * q + reg;
                float dv = diag[(size_t)bh * LL + gi];
                float* ob = out + obase + (size_t)gi * LL + j_base;
                #pragma unroll
                for (int nt = 0; nt < 4; ++nt) {
                    int gj = j_base + 16 * nt + l15;
                    float v = acc[mt][nt][reg];
                    nt_store(ob + 16 * nt + l15,
                             (gj < gi) ? v : ((gj == gi) ? dv : 0.f));
                }
            }
    }
}

extern "C" void kernel_launch(void* const* d_in, const int* in_sizes, int n_in,
                              void* d_out, int out_size, void* d_ws, size_t ws_size,
                              hipStream_t stream) {
    const float* Bg = (const float*)d_in[0];
    const float* Cg = (const float*)d_in[1];
    const float* S  = (const float*)d_in[2];
    float* out = (float*)d_out;

    char* ws = (char*)d_ws;
    size_t xy_bytes = (size_t)BHN * LL * HD * sizeof(__hip_bfloat16);  // 4 MB each
    __hip_bfloat16* X = (__hip_bfloat16*)(ws);
    __hip_bfloat16* Y = (__hip_bfloat16*)(ws + xy_bytes);
    float* diag = (float*)(ws + 2 * xy_bytes);
    float* U    = (float*)(ws + 2 * xy_bytes + (size_t)BHN * LL * sizeof(float));
    float* St   = (float*)(ws + 2 * xy_bytes + (size_t)BHN * LL * sizeof(float)
                              + (size_t)BHN * NC * HD * sizeof(float));

    chunkprod_kernel<<<dim3(NC, BHN), 64, 0, stream>>>(S, U);
    chunkscan_kernel<<<BHN, 1024, 0, stream>>>(U, St);
    diag_kernel<<<(LL * BHN) / 4, 256, 0, stream>>>(Bg, Cg, diag);
    apply_kernel<<<dim3(NC, BHN), 64, 0, stream>>>(Bg, Cg, S, St, X, Y);
    gemm_kernel<<<dim3(16, 16, BHN), 256, 0, stream>>>(X, Y, diag, out);
}